// Round 1
// baseline (57.575 us; speedup 1.0000x reference)
//
#include <hip/hip_runtime.h>
#include <math.h>

// Problem dims (fixed by reference):
// B=16, T=64, R=256, C=16, D_OUT=16, D_IN(=o)=16, NUM_ITERATIONS=3
//
// Factorization: u_hat[b,t,r,c,o] = Wsum[r,c,o]*usum[b,t]
//   Wsum[r,c,o] = sum_d W[r,c,d,o], usum[b,t] = sum_i ui[b,t,i]
// Per routing iter:
//   c_ij = softmax_c(b_ij); S[b,c,o] = sum_r c_ij*Wsum; NS[b,c]=sum_o S^2
//   scale(b,t,c) = squash_scale(usum^2*NS)
//   b_ij += WS[b,r,c]*Tsum[b,c],  WS = sum_o Wsum*S, Tsum = sum_t usum^2*scale
// Iter 0: c_ij uniform 1/16 -> S0[c,o] = (sum_r Wsum)/16 (b-independent).
// Output: v[b,t,c,o] = scale(b,t,c)*usum[b,t]*S2[b,c,o]

// workspace float offsets
#define OFF_WSUM   0        // [256][16][16] = 65536   (r,c,o)
#define OFF_WSUMT  65536    // [16][16][256] = 65536   (c,o,r)  transposed copy
#define OFF_USUM   131072   // [16][64]      = 1024
#define OFF_S0     132096   // [16][16]      = 256     (c,o)
#define OFF_TS     132352   // [16][16]      = 256     (b,c)
#define OFF_BIJ    132608   // [16][256][16] = 65536   (b,r,c)
// total = 198144 floats = 774 KiB

__device__ __forceinline__ float squash_scale(float n2) {
    return n2 / (1.0f + n2) * rsqrtf(n2 + 1e-9f);
}

// K1: Wsum (both layouts) + usum. grid 260x256
__global__ void k1_prep(const float* __restrict__ ui, const float* __restrict__ W,
                        float* __restrict__ ws) {
    const int blk = blockIdx.x;
    const int tid = threadIdx.x;
    if (blk < 256) {
        const int r = blk;
        const int c = tid >> 4, o = tid & 15;
        const float* base = W + r * 4096 + c * 256 + o;
        float s = 0.f;
#pragma unroll
        for (int d = 0; d < 16; ++d) s += base[d * 16];
        ws[OFF_WSUM + r * 256 + tid] = s;
        ws[OFF_WSUMT + tid * 256 + r] = s;
    } else {
        const int p = (blk - 256) * 256 + tid;   // (b,t) pair, 0..1023
        const float* base = ui + p * 16;
        float s = 0.f;
#pragma unroll
        for (int i = 0; i < 16; ++i) s += base[i];
        ws[OFF_USUM + p] = s;
    }
}

// K2: closed-form iteration 0: S0[c,o] = WsumR/16, Tsum0[b,c]. grid 1x256
__global__ void k2_round0(float* __restrict__ ws) {
    __shared__ float s0[256];
    __shared__ float ns0[16];
    const int tid = threadIdx.x;               // (c,o)
    const float4* wt4 = (const float4*)(ws + OFF_WSUMT + tid * 256);
    float acc = 0.f;
#pragma unroll 8
    for (int r4 = 0; r4 < 64; ++r4) {
        float4 w = wt4[r4];
        acc += (w.x + w.y) + (w.z + w.w);
    }
    const float s0v = acc * (1.0f / 16.0f);
    s0[tid] = s0v;
    ws[OFF_S0 + tid] = s0v;
    __syncthreads();
    if (tid < 16) {
        float ns = 0.f;
#pragma unroll
        for (int o = 0; o < 16; ++o) { float v = s0[tid * 16 + o]; ns += v * v; }
        ns0[tid] = ns;
    }
    __syncthreads();
    const int b = tid >> 4, c = tid & 15;      // (b,c)
    const float nsc = ns0[c];
    float ts = 0.f;
    for (int t = 0; t < 64; ++t) {
        const float us = ws[OFF_USUM + b * 64 + t];
        const float us2 = us * us;
        ts += us2 * squash_scale(us2 * nsc);
    }
    ws[OFF_TS + tid] = ts;
}

// K3: b_ij after iter 0: bij[b,r,c] = WS0[r,c]*Tsum0[b,c]. grid 16x256
__global__ void k3_bij1(float* __restrict__ ws) {
    __shared__ float s0[256];
    __shared__ float tsum[256];
    const int tid = threadIdx.x;
    s0[tid] = ws[OFF_S0 + tid];
    tsum[tid] = ws[OFF_TS + tid];
    __syncthreads();
    const int rl = tid >> 4, c = tid & 15;
    const int r = blockIdx.x * 16 + rl;
    const float4* w4 = (const float4*)(ws + OFF_WSUM + r * 256 + c * 16);
    float ws0 = 0.f;
#pragma unroll
    for (int q = 0; q < 4; ++q) {
        float4 w = w4[q];
        ws0 += w.x * s0[c * 16 + q * 4 + 0] + w.y * s0[c * 16 + q * 4 + 1]
             + w.z * s0[c * 16 + q * 4 + 2] + w.w * s0[c * 16 + q * 4 + 3];
    }
#pragma unroll
    for (int b = 0; b < 16; ++b) {
        ws[OFF_BIJ + b * 4096 + r * 16 + c] = ws0 * tsum[b * 16 + c];
    }
}

// K4: one routing iteration for one b per block. grid 16x256.
// FINAL=false: update bij.  FINAL=true: write v_j output.
template <bool FINAL>
__global__ void k4_iter(float* __restrict__ ws, float* __restrict__ out) {
    __shared__ float cijT[16][257];   // [c][r], padded
    __shared__ float sArr[256];       // S[c*16+o]
    __shared__ float nsArr[16];
    __shared__ float tsArr[16];
    const int b = blockIdx.x;
    const int tid = threadIdx.x;

    // Phase A: softmax over c of bij[b, r=tid, :]
    {
        const float4* r4 = (const float4*)(ws + OFF_BIJ + b * 4096 + tid * 16);
        float v[16];
        float4* rv = (float4*)v;
#pragma unroll
        for (int q = 0; q < 4; ++q) rv[q] = r4[q];
        float m = v[0];
#pragma unroll
        for (int c = 1; c < 16; ++c) m = fmaxf(m, v[c]);
        float sum = 0.f;
#pragma unroll
        for (int c = 0; c < 16; ++c) { v[c] = __expf(v[c] - m); sum += v[c]; }
        const float inv = 1.0f / sum;
#pragma unroll
        for (int c = 0; c < 16; ++c) cijT[c][tid] = v[c] * inv;
    }
    __syncthreads();

    // Phase B: S[c,o] = sum_r cij[r,c]*Wsum[r,c,o], tid=(c,o)
    {
        const int c = tid >> 4;
        const float4* wt4 = (const float4*)(ws + OFF_WSUMT + tid * 256);
        float acc = 0.f;
#pragma unroll 8
        for (int r4 = 0; r4 < 64; ++r4) {
            float4 w = wt4[r4];
            const int r = r4 * 4;
            acc += cijT[c][r] * w.x + cijT[c][r + 1] * w.y
                 + cijT[c][r + 2] * w.z + cijT[c][r + 3] * w.w;
        }
        sArr[tid] = acc;
    }
    __syncthreads();

    // Phase C: NS[c] (+ Tsum[c] if not final)
    if (tid < 16) {
        float ns = 0.f;
#pragma unroll
        for (int o = 0; o < 16; ++o) { float v = sArr[tid * 16 + o]; ns += v * v; }
        nsArr[tid] = ns;
        if (!FINAL) {
            float ts = 0.f;
            for (int t = 0; t < 64; ++t) {
                const float us = ws[OFF_USUM + b * 64 + t];
                const float us2 = us * us;
                ts += us2 * squash_scale(us2 * ns);
            }
            tsArr[tid] = ts;
        }
    }
    __syncthreads();

    if (!FINAL) {
        // Phase E: bij[b,r,c] += (sum_o Wsum[r,c,o]*S[c,o]) * Tsum[c]
        for (int k = 0; k < 16; ++k) {
            const int idx = k * 256 + tid;       // r*16+c
            const int c = idx & 15;
            const float4* w4 = (const float4*)(ws + OFF_WSUM + idx * 16);
            float wsv = 0.f;
#pragma unroll
            for (int q = 0; q < 4; ++q) {
                float4 w = w4[q];
                wsv += w.x * sArr[c * 16 + q * 4 + 0] + w.y * sArr[c * 16 + q * 4 + 1]
                     + w.z * sArr[c * 16 + q * 4 + 2] + w.w * sArr[c * 16 + q * 4 + 3];
            }
            ws[OFF_BIJ + b * 4096 + idx] += wsv * tsArr[c];
        }
    } else {
        // Output: v[b,t,c,o] = squash_scale(us^2*NS[c]) * us * S[c,o]
        for (int k = 0; k < 4; ++k) {
            const int p = k * 256 + tid;         // (t,c)
            const int t = p >> 4, c = p & 15;
            const float us = ws[OFF_USUM + b * 64 + t];
            const float n2 = us * us * nsArr[c];
            const float f = squash_scale(n2) * us;
            float4* o4 = (float4*)(out + (((b * 64 + t) * 16 + c) << 4));
            const float4* s4 = (const float4*)(sArr + c * 16);
#pragma unroll
            for (int q = 0; q < 4; ++q) {
                float4 sv = s4[q];
                float4 ov;
                ov.x = f * sv.x; ov.y = f * sv.y; ov.z = f * sv.z; ov.w = f * sv.w;
                o4[q] = ov;
            }
        }
    }
}

extern "C" void kernel_launch(void* const* d_in, const int* in_sizes, int n_in,
                              void* d_out, int out_size, void* d_ws, size_t ws_size,
                              hipStream_t stream) {
    const float* ui = (const float*)d_in[0];   // [16,64,16]
    const float* W  = (const float*)d_in[1];   // [1,256,16,16,16]
    float* out = (float*)d_out;                // [16,64,16,16]
    float* ws  = (float*)d_ws;

    k1_prep<<<260, 256, 0, stream>>>(ui, W, ws);
    k2_round0<<<1, 256, 0, stream>>>(ws);
    k3_bij1<<<16, 256, 0, stream>>>(ws);
    k4_iter<false><<<16, 256, 0, stream>>>(ws, out);
    k4_iter<true><<<16, 256, 0, stream>>>(ws, out);
}